// Round 1
// baseline (1704.685 us; speedup 1.0000x reference)
//
#include <hip/hip_runtime.h>
#include <hip/hip_bf16.h>

// Problem constants (from reference)
constexpr int NN   = 100000;   // nodes
constexpr int IND  = 256;      // input dim
constexpr int HIDD = 256;      // hidden dim
constexpr int EMBD = 64;       // embedding dim
constexpr int EE   = 3200000;  // edges
#define EPS_BN 1e-3f

// ---------------- GEMM1: h0(bf16) = x @ w1  [100000x256 @ 256x256] ----------
// Block = 256 threads, tile = 32 rows x 256 cols. thread col = tid.
// x addresses are wave-uniform -> scalar loads through constant cache.
__global__ __launch_bounds__(256) void gemm1_kernel(
    const float* __restrict__ x, const float* __restrict__ w1,
    __hip_bfloat16* __restrict__ h0) {
  const int rb  = blockIdx.x * 32;       // 3125 blocks * 32 = 100000 exact
  const int col = threadIdx.x;
  float acc[32];
#pragma unroll
  for (int r = 0; r < 32; ++r) acc[r] = 0.f;
  const float* xb = x + (size_t)rb * IND;
  for (int k = 0; k < IND; k += 4) {
    const float w0 = w1[(k + 0) * HIDD + col];
    const float w1v = w1[(k + 1) * HIDD + col];
    const float w2v = w1[(k + 2) * HIDD + col];
    const float w3v = w1[(k + 3) * HIDD + col];
#pragma unroll
    for (int r = 0; r < 32; ++r) {
      const float* xr = xb + r * IND + k;   // wave-uniform -> s_load
      acc[r] = fmaf(xr[0], w0, acc[r]);
      acc[r] = fmaf(xr[1], w1v, acc[r]);
      acc[r] = fmaf(xr[2], w2v, acc[r]);
      acc[r] = fmaf(xr[3], w3v, acc[r]);
    }
  }
#pragma unroll
  for (int r = 0; r < 32; ++r)
    h0[(size_t)(rb + r) * HIDD + col] = __float2bfloat16(acc[r]);
}

// ---------------- GEMM2: z0(f32) = h @ w2  [100000x256 @ 256x64] ------------
// Block = 256 threads = 4 waves; wave s handles rows rb+8s..rb+8s+7, lane=col.
__global__ __launch_bounds__(256) void gemm2_kernel(
    const float* __restrict__ h, const float* __restrict__ w2,
    float* __restrict__ z0) {
  const int rb    = blockIdx.x * 32;     // 3125 blocks * 32 = 100000 exact
  const int col   = threadIdx.x & 63;
  const int slice = threadIdx.x >> 6;    // wave-uniform
  float acc[8];
#pragma unroll
  for (int r = 0; r < 8; ++r) acc[r] = 0.f;
  const float* hb = h + (size_t)(rb + slice * 8) * HIDD;
  for (int k = 0; k < HIDD; k += 4) {
    const float w0 = w2[(k + 0) * EMBD + col];
    const float w1v = w2[(k + 1) * EMBD + col];
    const float w2v = w2[(k + 2) * EMBD + col];
    const float w3v = w2[(k + 3) * EMBD + col];
#pragma unroll
    for (int r = 0; r < 8; ++r) {
      const float* hr = hb + r * HIDD + k;  // wave-uniform -> s_load
      acc[r] = fmaf(hr[0], w0, acc[r]);
      acc[r] = fmaf(hr[1], w1v, acc[r]);
      acc[r] = fmaf(hr[2], w2v, acc[r]);
      acc[r] = fmaf(hr[3], w3v, acc[r]);
    }
  }
#pragma unroll
  for (int r = 0; r < 8; ++r)
    z0[(size_t)(rb + slice * 8 + r) * EMBD + col] = acc[r];
}

// ---------------- CSR build --------------------------------------------------
__global__ void hist_kernel(const int* __restrict__ row, int* __restrict__ cnt) {
  int e = blockIdx.x * blockDim.x + threadIdx.x;
  if (e < EE) atomicAdd(&cnt[row[e]], 1);
}

// inclusive scan per 1024-block (Hillis-Steele), block sums out
__global__ __launch_bounds__(1024) void scan1_kernel(
    const int* __restrict__ cnt, int* __restrict__ tmp, int* __restrict__ bsum) {
  __shared__ int lds[1024];
  int gid = blockIdx.x * 1024 + threadIdx.x;
  int v = (gid < NN) ? cnt[gid] : 0;
  lds[threadIdx.x] = v;
  for (int off = 1; off < 1024; off <<= 1) {
    __syncthreads();
    int t = (threadIdx.x >= off) ? lds[threadIdx.x - off] : 0;
    __syncthreads();
    lds[threadIdx.x] += t;
  }
  __syncthreads();
  if (gid < NN) tmp[gid] = lds[threadIdx.x];
  if (threadIdx.x == 1023) bsum[blockIdx.x] = lds[1023];
}

// scan 98 block sums -> exclusive prefixes
__global__ __launch_bounds__(128) void scan2_kernel(
    const int* __restrict__ bsum, int* __restrict__ bpre) {
  __shared__ int lds[128];
  const int nb = (NN + 1023) / 1024;  // 98
  int v = (threadIdx.x < nb) ? bsum[threadIdx.x] : 0;
  lds[threadIdx.x] = v;
  for (int off = 1; off < 128; off <<= 1) {
    __syncthreads();
    int t = (threadIdx.x >= off) ? lds[threadIdx.x - off] : 0;
    __syncthreads();
    lds[threadIdx.x] += t;
  }
  __syncthreads();
  if (threadIdx.x < nb) bpre[threadIdx.x] = lds[threadIdx.x] - v;  // exclusive
}

__global__ __launch_bounds__(1024) void scan3_kernel(
    const int* __restrict__ tmp, const int* __restrict__ cnt,
    const int* __restrict__ bpre, int* __restrict__ row_start,
    int* __restrict__ cursor) {
  int gid = blockIdx.x * 1024 + threadIdx.x;
  if (gid < NN) {
    int ex = tmp[gid] - cnt[gid] + bpre[blockIdx.x];  // exclusive scan
    row_start[gid] = ex;
    cursor[gid] = ex;
  }
  if (gid == 0) row_start[NN] = EE;
}

__global__ void scatter_kernel(
    const int* __restrict__ row, const int* __restrict__ col,
    const float* __restrict__ val, int* __restrict__ cursor,
    int* __restrict__ col_s, float* __restrict__ val_s) {
  int e = blockIdx.x * blockDim.x + threadIdx.x;
  if (e < EE) {
    int r = row[e];
    int p = atomicAdd(&cursor[r], 1);
    col_s[p] = col[e];
    val_s[p] = val[e];
  }
}

// ---------------- SpMM1 + BN1 + ReLU: h = relu(bn1(A @ h0)) ------------------
// One wave per row. Lane i owns dims 4i..4i+3. Gather 8B/lane (ushort4 of bf16).
__global__ __launch_bounds__(256) void spmm1_kernel(
    const __hip_bfloat16* __restrict__ h0, const int* __restrict__ row_start,
    const int* __restrict__ col_s, const float* __restrict__ val_s,
    const float* __restrict__ gamma, const float* __restrict__ beta,
    const float* __restrict__ mean, const float* __restrict__ var,
    float* __restrict__ h) {
  const int row  = (blockIdx.x * blockDim.x + threadIdx.x) >> 6;  // 25000*4 waves = 100000
  const int lane = threadIdx.x & 63;
  const int s = row_start[row];
  const int e = row_start[row + 1];
  float a0 = 0.f, a1 = 0.f, a2 = 0.f, a3 = 0.f;
  for (int p = s; p < e; ++p) {
    const int   c = col_s[p];
    const float v = val_s[p];
    ushort4 u = *(const ushort4*)(h0 + (size_t)c * HIDD + lane * 4);
    a0 = fmaf(v, __uint_as_float(((unsigned)u.x) << 16), a0);
    a1 = fmaf(v, __uint_as_float(((unsigned)u.y) << 16), a1);
    a2 = fmaf(v, __uint_as_float(((unsigned)u.z) << 16), a2);
    a3 = fmaf(v, __uint_as_float(((unsigned)u.w) << 16), a3);
  }
  const int d = lane * 4;
  float4 g = *(const float4*)(gamma + d);
  float4 b = *(const float4*)(beta + d);
  float4 m = *(const float4*)(mean + d);
  float4 vv = *(const float4*)(var + d);
  float4 o;
  o.x = fmaxf(fmaf((a0 - m.x) * rsqrtf(vv.x + EPS_BN), g.x, b.x), 0.f);
  o.y = fmaxf(fmaf((a1 - m.y) * rsqrtf(vv.y + EPS_BN), g.y, b.y), 0.f);
  o.z = fmaxf(fmaf((a2 - m.z) * rsqrtf(vv.z + EPS_BN), g.z, b.z), 0.f);
  o.w = fmaxf(fmaf((a3 - m.w) * rsqrtf(vv.w + EPS_BN), g.w, b.w), 0.f);
  *(float4*)(h + (size_t)row * HIDD + d) = o;
}

// ---------------- SpMM2 + BN2: out = bn2(A @ z0) -----------------------------
// One wave per row; lane = embedding dim (64).
__global__ __launch_bounds__(256) void spmm2_kernel(
    const float* __restrict__ z0, const int* __restrict__ row_start,
    const int* __restrict__ col_s, const float* __restrict__ val_s,
    const float* __restrict__ gamma, const float* __restrict__ beta,
    const float* __restrict__ mean, const float* __restrict__ var,
    float* __restrict__ out) {
  const int row  = (blockIdx.x * blockDim.x + threadIdx.x) >> 6;
  const int lane = threadIdx.x & 63;
  const int s = row_start[row];
  const int e = row_start[row + 1];
  float acc = 0.f;
  for (int p = s; p < e; ++p) {
    const int   c = col_s[p];
    const float v = val_s[p];
    acc = fmaf(v, z0[(size_t)c * EMBD + lane], acc);
  }
  float r = fmaf((acc - mean[lane]) * rsqrtf(var[lane] + EPS_BN), gamma[lane],
                 beta[lane]);
  out[(size_t)row * EMBD + lane] = r;
}

extern "C" void kernel_launch(void* const* d_in, const int* in_sizes, int n_in,
                              void* d_out, int out_size, void* d_ws, size_t ws_size,
                              hipStream_t stream) {
  const float* x        = (const float*)d_in[0];
  const int*   edge_row = (const int*)d_in[1];
  const int*   edge_col = (const int*)d_in[2];
  const float* edge_val = (const float*)d_in[3];
  const float* w1       = (const float*)d_in[4];
  const float* w2       = (const float*)d_in[5];
  const float* gamma1   = (const float*)d_in[6];
  const float* beta1    = (const float*)d_in[7];
  const float* mean1    = (const float*)d_in[8];
  const float* var1     = (const float*)d_in[9];
  const float* gamma2   = (const float*)d_in[10];
  const float* beta2    = (const float*)d_in[11];
  const float* mean2    = (const float*)d_in[12];
  const float* var2     = (const float*)d_in[13];
  float* out = (float*)d_out;

  // Workspace layout (256B aligned). Total ~181 MB.
  char* ws = (char*)d_ws;
  size_t off = 0;
  auto alloc = [&](size_t bytes) -> void* {
    void* p = ws + off;
    off = (off + bytes + 255) & ~(size_t)255;
    return p;
  };
  __hip_bfloat16* h0 = (__hip_bfloat16*)alloc((size_t)NN * HIDD * 2);  // 51.2MB
  float* z0 = (float*)h0;   // aliased: h0 dead before gemm2 writes z0 (25.6MB <= 51.2MB)
  float* h        = (float*)alloc((size_t)NN * HIDD * 4);              // 102.4MB
  int*   cnt      = (int*)alloc((size_t)NN * 4);
  int*   tmp      = (int*)alloc((size_t)NN * 4);
  int*   bsum     = (int*)alloc(128 * 4);
  int*   bpre     = (int*)alloc(128 * 4);
  int*   row_start= (int*)alloc((size_t)(NN + 1) * 4);
  int*   cursor   = (int*)alloc((size_t)NN * 4);
  int*   col_s    = (int*)alloc((size_t)EE * 4);
  float* val_s    = (float*)alloc((size_t)EE * 4);

  const int nb_scan = (NN + 1023) / 1024;  // 98

  // CSR build
  hipMemsetAsync(cnt, 0, (size_t)NN * 4, stream);
  hist_kernel<<<(EE + 255) / 256, 256, 0, stream>>>(edge_row, cnt);
  scan1_kernel<<<nb_scan, 1024, 0, stream>>>(cnt, tmp, bsum);
  scan2_kernel<<<1, 128, 0, stream>>>(bsum, bpre);
  scan3_kernel<<<nb_scan, 1024, 0, stream>>>(tmp, cnt, bpre, row_start, cursor);
  scatter_kernel<<<(EE + 255) / 256, 256, 0, stream>>>(
      edge_row, edge_col, edge_val, cursor, col_s, val_s);

  // Layer 1
  gemm1_kernel<<<NN / 32, 256, 0, stream>>>(x, w1, h0);
  spmm1_kernel<<<NN / 4, 256, 0, stream>>>(h0, row_start, col_s, val_s,
                                           gamma1, beta1, mean1, var1, h);
  // Layer 2
  gemm2_kernel<<<NN / 32, 256, 0, stream>>>(h, w2, z0);
  spmm2_kernel<<<NN / 4, 256, 0, stream>>>(z0, row_start, col_s, val_s,
                                           gamma2, beta2, mean2, var2, out);
}

// Round 2
// 1201.879 us; speedup vs baseline: 1.4183x; 1.4183x over previous
//
#include <hip/hip_runtime.h>
#include <hip/hip_bf16.h>

// Problem constants (from reference)
constexpr int NN   = 100000;   // nodes
constexpr int IND  = 256;      // input dim
constexpr int HIDD = 256;      // hidden dim
constexpr int EMBD = 64;       // embedding dim
constexpr int EE   = 3200000;  // edges
#define EPS_BN 1e-3f

typedef short  short8  __attribute__((ext_vector_type(8)));
typedef float  floatx4 __attribute__((ext_vector_type(4)));

static __device__ __forceinline__ unsigned short f2bf(float f) {
  __hip_bfloat16 b = __float2bfloat16(f);
  union { __hip_bfloat16 b; unsigned short u; } cv;
  cv.b = b;
  return cv.u;
}
static __device__ __forceinline__ float bf2f(unsigned short u) {
  return __uint_as_float(((unsigned)u) << 16);
}

// ---------------- cast x: f32 -> bf16 (row-major unchanged) -----------------
__global__ __launch_bounds__(256) void cast_x_kernel(
    const float* __restrict__ x, unsigned short* __restrict__ xb) {
  const int i = blockIdx.x * blockDim.x + threadIdx.x;  // over 6.4M float4s
  float4 v = ((const float4*)x)[i];
  ushort4 o;
  o.x = f2bf(v.x); o.y = f2bf(v.y); o.z = f2bf(v.z); o.w = f2bf(v.w);
  ((ushort4*)xb)[i] = o;
}

// ---- swizzle weights into MFMA B-fragment layout -----------------------------
// frag id f = kt*NT + nt. Lane l supplies B[k=kt*32+(l>>4)*8+j][n=nt*16+(l&15)],
// stored contiguously: out[(f*64 + l)*8 + j]  ->  one ds/global 16B read per frag.
__global__ __launch_bounds__(256) void swz_w1_kernel(
    const float* __restrict__ w1, unsigned short* __restrict__ w1s) {
  const int t = blockIdx.x * blockDim.x + threadIdx.x;  // 8192 threads
  const int lane = t & 63;
  const int f = t >> 6;          // 0..127
  const int kt = f >> 4;         // 0..7
  const int nt = f & 15;         // 0..15
  const int n = nt * 16 + (lane & 15);
#pragma unroll
  for (int j = 0; j < 8; ++j) {
    const int k = kt * 32 + (lane >> 4) * 8 + j;
    w1s[(size_t)(f * 64 + lane) * 8 + j] = f2bf(w1[k * HIDD + n]);
  }
}

__global__ __launch_bounds__(256) void swz_w2_kernel(
    const float* __restrict__ w2, unsigned short* __restrict__ w2s) {
  const int t = blockIdx.x * blockDim.x + threadIdx.x;  // 2048 threads
  const int lane = t & 63;
  const int f = t >> 6;          // 0..31
  const int kt = f >> 2;         // 0..7
  const int nt = f & 3;          // 0..3
  const int n = nt * 16 + (lane & 15);
#pragma unroll
  for (int j = 0; j < 8; ++j) {
    const int k = kt * 32 + (lane >> 4) * 8 + j;
    w2s[(size_t)(f * 64 + lane) * 8 + j] = f2bf(w2[k * EMBD + n]);
  }
}

// ---------------- GEMM1 (MFMA): h0(bf16) = xb @ w1  [100000x256 @ 256x256] ---
// 512 threads = 8 waves. Wave w owns n-tiles {2w, 2w+1}; B-frags in registers.
// Block sweeps 10 m-tiles (160 rows); A-frags loaded direct from global.
__global__ __launch_bounds__(512) void gemm1_mfma(
    const unsigned short* __restrict__ xb, const unsigned short* __restrict__ w1s,
    unsigned short* __restrict__ h0) {
  const int lane = threadIdx.x & 63;
  const int wave = threadIdx.x >> 6;   // 0..7
  const int quad = lane >> 4;
  const int l15  = lane & 15;
  const short8* w1v = (const short8*)w1s;
  short8 bf[2][8];
#pragma unroll
  for (int nt2 = 0; nt2 < 2; ++nt2)
#pragma unroll
    for (int kt = 0; kt < 8; ++kt)
      bf[nt2][kt] = w1v[(size_t)(kt * 16 + wave * 2 + nt2) * 64 + lane];
  for (int i = 0; i < 10; ++i) {
    const int m0 = (blockIdx.x * 10 + i) * 16;
    const unsigned short* ap = xb + (size_t)(m0 + l15) * IND + quad * 8;
    short8 af[8];
#pragma unroll
    for (int kt = 0; kt < 8; ++kt)
      af[kt] = *(const short8*)(ap + kt * 32);
    floatx4 c0 = {0.f, 0.f, 0.f, 0.f};
    floatx4 c1 = {0.f, 0.f, 0.f, 0.f};
#pragma unroll
    for (int kt = 0; kt < 8; ++kt) {
      c0 = __builtin_amdgcn_mfma_f32_16x16x32_bf16(af[kt], bf[0][kt], c0, 0, 0, 0);
      c1 = __builtin_amdgcn_mfma_f32_16x16x32_bf16(af[kt], bf[1][kt], c1, 0, 0, 0);
    }
    // C/D layout: col = lane&15, row = quad*4 + reg  [verified m89/m91]
    unsigned short* o = h0 + (size_t)(m0 + quad * 4) * HIDD + wave * 32 + l15;
#pragma unroll
    for (int r = 0; r < 4; ++r) {
      o[(size_t)r * HIDD]      = f2bf(c0[r]);
      o[(size_t)r * HIDD + 16] = f2bf(c1[r]);
    }
  }
}

// ---------------- GEMM2 (MFMA): z0(f32) = h(bf16) @ w2  [100000x256 @ 256x64]
// 256 threads = 4 waves; wave w owns n-tile w. Block sweeps 10 m-tiles.
__global__ __launch_bounds__(256) void gemm2_mfma(
    const unsigned short* __restrict__ hb, const unsigned short* __restrict__ w2s,
    float* __restrict__ z0) {
  const int lane = threadIdx.x & 63;
  const int wave = threadIdx.x >> 6;   // 0..3
  const int quad = lane >> 4;
  const int l15  = lane & 15;
  const short8* w2v = (const short8*)w2s;
  short8 bf[8];
#pragma unroll
  for (int kt = 0; kt < 8; ++kt)
    bf[kt] = w2v[(size_t)(kt * 4 + wave) * 64 + lane];
  for (int i = 0; i < 10; ++i) {
    const int m0 = (blockIdx.x * 10 + i) * 16;
    const unsigned short* ap = hb + (size_t)(m0 + l15) * HIDD + quad * 8;
    short8 af[8];
#pragma unroll
    for (int kt = 0; kt < 8; ++kt)
      af[kt] = *(const short8*)(ap + kt * 32);
    floatx4 c = {0.f, 0.f, 0.f, 0.f};
#pragma unroll
    for (int kt = 0; kt < 8; ++kt)
      c = __builtin_amdgcn_mfma_f32_16x16x32_bf16(af[kt], bf[kt], c, 0, 0, 0);
    float* o = z0 + (size_t)(m0 + quad * 4) * EMBD + wave * 16 + l15;
#pragma unroll
    for (int r = 0; r < 4; ++r) o[(size_t)r * EMBD] = c[r];
  }
}

// ---------------- CSR build --------------------------------------------------
__global__ void hist_kernel(const int* __restrict__ row, int* __restrict__ cnt) {
  int e = blockIdx.x * blockDim.x + threadIdx.x;
  if (e < EE) atomicAdd(&cnt[row[e]], 1);
}

__global__ __launch_bounds__(1024) void scan1_kernel(
    const int* __restrict__ cnt, int* __restrict__ tmp, int* __restrict__ bsum) {
  __shared__ int lds[1024];
  int gid = blockIdx.x * 1024 + threadIdx.x;
  int v = (gid < NN) ? cnt[gid] : 0;
  lds[threadIdx.x] = v;
  for (int off = 1; off < 1024; off <<= 1) {
    __syncthreads();
    int t = (threadIdx.x >= off) ? lds[threadIdx.x - off] : 0;
    __syncthreads();
    lds[threadIdx.x] += t;
  }
  __syncthreads();
  if (gid < NN) tmp[gid] = lds[threadIdx.x];
  if (threadIdx.x == 1023) bsum[blockIdx.x] = lds[1023];
}

__global__ __launch_bounds__(128) void scan2_kernel(
    const int* __restrict__ bsum, int* __restrict__ bpre) {
  __shared__ int lds[128];
  const int nb = (NN + 1023) / 1024;  // 98
  int v = (threadIdx.x < nb) ? bsum[threadIdx.x] : 0;
  lds[threadIdx.x] = v;
  for (int off = 1; off < 128; off <<= 1) {
    __syncthreads();
    int t = (threadIdx.x >= off) ? lds[threadIdx.x - off] : 0;
    __syncthreads();
    lds[threadIdx.x] += t;
  }
  __syncthreads();
  if (threadIdx.x < nb) bpre[threadIdx.x] = lds[threadIdx.x] - v;  // exclusive
}

__global__ __launch_bounds__(1024) void scan3_kernel(
    const int* __restrict__ tmp, const int* __restrict__ cnt,
    const int* __restrict__ bpre, int* __restrict__ row_start,
    int* __restrict__ cursor) {
  int gid = blockIdx.x * 1024 + threadIdx.x;
  if (gid < NN) {
    int ex = tmp[gid] - cnt[gid] + bpre[blockIdx.x];  // exclusive scan
    row_start[gid] = ex;
    cursor[gid] = ex;
  }
  if (gid == 0) row_start[NN] = EE;
}

__global__ void scatter_kernel(
    const int* __restrict__ row, const int* __restrict__ col,
    const float* __restrict__ val, int* __restrict__ cursor,
    int* __restrict__ col_s, float* __restrict__ val_s) {
  int e = blockIdx.x * blockDim.x + threadIdx.x;
  if (e < EE) {
    int r = row[e];
    int p = atomicAdd(&cursor[r], 1);
    col_s[p] = col[e];
    val_s[p] = val[e];
  }
}

// ---------------- SpMM1 + BN1 + ReLU: h(bf16) = relu(bn1(A @ h0)) ------------
// One wave per row. Lane i owns dims 4i..4i+3. Gather 8B/lane (ushort4 of bf16).
__global__ __launch_bounds__(256) void spmm1_kernel(
    const unsigned short* __restrict__ h0, const int* __restrict__ row_start,
    const int* __restrict__ col_s, const float* __restrict__ val_s,
    const float* __restrict__ gamma, const float* __restrict__ beta,
    const float* __restrict__ mean, const float* __restrict__ var,
    unsigned short* __restrict__ h) {
  const int row  = (blockIdx.x * blockDim.x + threadIdx.x) >> 6;
  const int lane = threadIdx.x & 63;
  const int s = row_start[row];
  const int e = row_start[row + 1];
  float a0 = 0.f, a1 = 0.f, a2 = 0.f, a3 = 0.f;
  for (int p = s; p < e; ++p) {
    const int   c = col_s[p];
    const float v = val_s[p];
    ushort4 u = *(const ushort4*)(h0 + (size_t)c * HIDD + lane * 4);
    a0 = fmaf(v, bf2f(u.x), a0);
    a1 = fmaf(v, bf2f(u.y), a1);
    a2 = fmaf(v, bf2f(u.z), a2);
    a3 = fmaf(v, bf2f(u.w), a3);
  }
  const int d = lane * 4;
  float4 g = *(const float4*)(gamma + d);
  float4 b = *(const float4*)(beta + d);
  float4 m = *(const float4*)(mean + d);
  float4 vv = *(const float4*)(var + d);
  ushort4 o;
  o.x = f2bf(fmaxf(fmaf((a0 - m.x) * rsqrtf(vv.x + EPS_BN), g.x, b.x), 0.f));
  o.y = f2bf(fmaxf(fmaf((a1 - m.y) * rsqrtf(vv.y + EPS_BN), g.y, b.y), 0.f));
  o.z = f2bf(fmaxf(fmaf((a2 - m.z) * rsqrtf(vv.z + EPS_BN), g.z, b.z), 0.f));
  o.w = f2bf(fmaxf(fmaf((a3 - m.w) * rsqrtf(vv.w + EPS_BN), g.w, b.w), 0.f));
  *(ushort4*)(h + (size_t)row * HIDD + d) = o;
}

// ---------------- SpMM2 + BN2: out = bn2(A @ z0) -----------------------------
__global__ __launch_bounds__(256) void spmm2_kernel(
    const float* __restrict__ z0, const int* __restrict__ row_start,
    const int* __restrict__ col_s, const float* __restrict__ val_s,
    const float* __restrict__ gamma, const float* __restrict__ beta,
    const float* __restrict__ mean, const float* __restrict__ var,
    float* __restrict__ out) {
  const int row  = (blockIdx.x * blockDim.x + threadIdx.x) >> 6;
  const int lane = threadIdx.x & 63;
  const int s = row_start[row];
  const int e = row_start[row + 1];
  float acc = 0.f;
  for (int p = s; p < e; ++p) {
    const int   c = col_s[p];
    const float v = val_s[p];
    acc = fmaf(v, z0[(size_t)c * EMBD + lane], acc);
  }
  float r = fmaf((acc - mean[lane]) * rsqrtf(var[lane] + EPS_BN), gamma[lane],
                 beta[lane]);
  out[(size_t)row * EMBD + lane] = r;
}

extern "C" void kernel_launch(void* const* d_in, const int* in_sizes, int n_in,
                              void* d_out, int out_size, void* d_ws, size_t ws_size,
                              hipStream_t stream) {
  const float* x        = (const float*)d_in[0];
  const int*   edge_row = (const int*)d_in[1];
  const int*   edge_col = (const int*)d_in[2];
  const float* edge_val = (const float*)d_in[3];
  const float* w1       = (const float*)d_in[4];
  const float* w2       = (const float*)d_in[5];
  const float* gamma1   = (const float*)d_in[6];
  const float* beta1    = (const float*)d_in[7];
  const float* mean1    = (const float*)d_in[8];
  const float* var1     = (const float*)d_in[9];
  const float* gamma2   = (const float*)d_in[10];
  const float* beta2    = (const float*)d_in[11];
  const float* mean2    = (const float*)d_in[12];
  const float* var2     = (const float*)d_in[13];
  float* out = (float*)d_out;

  // Workspace layout (256B aligned). Total ~181 MB.
  char* ws = (char*)d_ws;
  size_t off = 0;
  auto alloc = [&](size_t bytes) -> void* {
    void* p = ws + off;
    off = (off + bytes + 255) & ~(size_t)255;
    return p;
  };
  unsigned short* xb  = (unsigned short*)alloc((size_t)NN * IND * 2);   // 51.2MB
  unsigned short* h0  = (unsigned short*)alloc((size_t)NN * HIDD * 2);  // 51.2MB
  float* z0 = (float*)h0;  // alias: h0 dead after spmm1; z0 = 25.6MB <= 51.2MB
  unsigned short* h   = (unsigned short*)alloc((size_t)NN * HIDD * 2);  // 51.2MB
  unsigned short* w1s = (unsigned short*)alloc((size_t)IND * HIDD * 2);
  unsigned short* w2s = (unsigned short*)alloc((size_t)HIDD * EMBD * 2);
  int*   cnt      = (int*)alloc((size_t)NN * 4);
  int*   tmp      = (int*)alloc((size_t)NN * 4);
  int*   bsum     = (int*)alloc(128 * 4);
  int*   bpre     = (int*)alloc(128 * 4);
  int*   row_start= (int*)alloc((size_t)(NN + 1) * 4);
  int*   cursor   = (int*)alloc((size_t)NN * 4);
  int*   col_s    = (int*)alloc((size_t)EE * 4);
  float* val_s    = (float*)alloc((size_t)EE * 4);

  const int nb_scan = (NN + 1023) / 1024;  // 98

  // casts + weight swizzles (independent of CSR build)
  cast_x_kernel<<<(NN * IND / 4) / 256, 256, 0, stream>>>(x, xb);
  swz_w1_kernel<<<8192 / 256, 256, 0, stream>>>(w1, w1s);
  swz_w2_kernel<<<2048 / 256, 256, 0, stream>>>(w2, w2s);

  // CSR build
  hipMemsetAsync(cnt, 0, (size_t)NN * 4, stream);
  hist_kernel<<<(EE + 255) / 256, 256, 0, stream>>>(edge_row, cnt);
  scan1_kernel<<<nb_scan, 1024, 0, stream>>>(cnt, tmp, bsum);
  scan2_kernel<<<1, 128, 0, stream>>>(bsum, bpre);
  scan3_kernel<<<nb_scan, 1024, 0, stream>>>(tmp, cnt, bpre, row_start, cursor);
  scatter_kernel<<<(EE + 255) / 256, 256, 0, stream>>>(
      edge_row, edge_col, edge_val, cursor, col_s, val_s);

  // Layer 1: h0 = xb @ w1 ; h = relu(bn1(A @ h0))
  gemm1_mfma<<<625, 512, 0, stream>>>(xb, w1s, h0);
  spmm1_kernel<<<NN / 4, 256, 0, stream>>>(h0, row_start, col_s, val_s,
                                           gamma1, beta1, mean1, var1, h);
  // Layer 2: z0 = h @ w2 ; out = bn2(A @ z0)
  gemm2_mfma<<<625, 256, 0, stream>>>(h, w2s, z0);
  spmm2_kernel<<<NN / 4, 256, 0, stream>>>(z0, row_start, col_s, val_s,
                                           gamma2, beta2, mean2, var2, out);
}

// Round 3
// 900.095 us; speedup vs baseline: 1.8939x; 1.3353x over previous
//
#include <hip/hip_runtime.h>
#include <hip/hip_bf16.h>

// Problem constants (from reference)
constexpr int NN   = 100000;   // nodes
constexpr int IND  = 256;      // input dim
constexpr int HIDD = 256;      // hidden dim
constexpr int EMBD = 64;       // embedding dim
constexpr int EE   = 3200000;  // edges
#define EPS_BN 1e-3f

typedef short  short8  __attribute__((ext_vector_type(8)));
typedef float  floatx4 __attribute__((ext_vector_type(4)));

static __device__ __forceinline__ unsigned short f2bf(float f) {
  __hip_bfloat16 b = __float2bfloat16(f);
  union { __hip_bfloat16 b; unsigned short u; } cv;
  cv.b = b;
  return cv.u;
}
static __device__ __forceinline__ float bf2f(unsigned short u) {
  return __uint_as_float(((unsigned)u) << 16);
}
static __device__ __forceinline__ unsigned char f2fp8(float f) {
  // v_cvt_pk_fp8_f32: OCP e4m3fn on gfx950
  return (unsigned char)__builtin_amdgcn_cvt_pk_fp8_f32(f, f, 0, false);
}

// ---------------- cast x: f32 -> bf16 (row-major unchanged) -----------------
__global__ __launch_bounds__(256) void cast_x_kernel(
    const float* __restrict__ x, unsigned short* __restrict__ xb) {
  const int i = blockIdx.x * blockDim.x + threadIdx.x;  // over 6.4M float4s
  float4 v = ((const float4*)x)[i];
  ushort4 o;
  o.x = f2bf(v.x); o.y = f2bf(v.y); o.z = f2bf(v.z); o.w = f2bf(v.w);
  ((ushort4*)xb)[i] = o;
}

// ---- swizzle weights into MFMA B-fragment layout -----------------------------
// frag id f = kt*NT + nt. Lane l supplies B[k=kt*32+(l>>4)*8+j][n=nt*16+(l&15)],
// stored contiguously: out[(f*64 + l)*8 + j]  ->  one 16B read per frag.
__global__ __launch_bounds__(256) void swz_w1_kernel(
    const float* __restrict__ w1, unsigned short* __restrict__ w1s) {
  const int t = blockIdx.x * blockDim.x + threadIdx.x;  // 8192 threads
  const int lane = t & 63;
  const int f = t >> 6;          // 0..127
  const int kt = f >> 4;         // 0..7
  const int nt = f & 15;         // 0..15
  const int n = nt * 16 + (lane & 15);
#pragma unroll
  for (int j = 0; j < 8; ++j) {
    const int k = kt * 32 + (lane >> 4) * 8 + j;
    w1s[(size_t)(f * 64 + lane) * 8 + j] = f2bf(w1[k * HIDD + n]);
  }
}

__global__ __launch_bounds__(256) void swz_w2_kernel(
    const float* __restrict__ w2, unsigned short* __restrict__ w2s) {
  const int t = blockIdx.x * blockDim.x + threadIdx.x;  // 2048 threads
  const int lane = t & 63;
  const int f = t >> 6;          // 0..31
  const int kt = f >> 2;         // 0..7
  const int nt = f & 3;          // 0..3
  const int n = nt * 16 + (lane & 15);
#pragma unroll
  for (int j = 0; j < 8; ++j) {
    const int k = kt * 32 + (lane >> 4) * 8 + j;
    w2s[(size_t)(f * 64 + lane) * 8 + j] = f2bf(w2[k * EMBD + n]);
  }
}

// ---------------- GEMM1 (MFMA): h0(fp8) = xb @ w1  [100000x256 @ 256x256] ----
// 512 threads = 8 waves. Wave w owns n-tiles {2w, 2w+1}; B-frags in registers.
// Block sweeps 10 m-tiles; A-frags loaded direct from global. Epilogue -> fp8.
__global__ __launch_bounds__(512) void gemm1_mfma(
    const unsigned short* __restrict__ xb, const unsigned short* __restrict__ w1s,
    unsigned char* __restrict__ h0) {
  const int lane = threadIdx.x & 63;
  const int wave = threadIdx.x >> 6;   // 0..7
  const int quad = lane >> 4;
  const int l15  = lane & 15;
  const short8* w1v = (const short8*)w1s;
  short8 bf[2][8];
#pragma unroll
  for (int nt2 = 0; nt2 < 2; ++nt2)
#pragma unroll
    for (int kt = 0; kt < 8; ++kt)
      bf[nt2][kt] = w1v[(size_t)(kt * 16 + wave * 2 + nt2) * 64 + lane];
  for (int i = 0; i < 10; ++i) {
    const int m0 = (blockIdx.x * 10 + i) * 16;
    const unsigned short* ap = xb + (size_t)(m0 + l15) * IND + quad * 8;
    short8 af[8];
#pragma unroll
    for (int kt = 0; kt < 8; ++kt)
      af[kt] = *(const short8*)(ap + kt * 32);
    floatx4 c0 = {0.f, 0.f, 0.f, 0.f};
    floatx4 c1 = {0.f, 0.f, 0.f, 0.f};
#pragma unroll
    for (int kt = 0; kt < 8; ++kt) {
      c0 = __builtin_amdgcn_mfma_f32_16x16x32_bf16(af[kt], bf[0][kt], c0, 0, 0, 0);
      c1 = __builtin_amdgcn_mfma_f32_16x16x32_bf16(af[kt], bf[1][kt], c1, 0, 0, 0);
    }
    // C/D layout: col = lane&15, row = quad*4 + reg  [verified m89/m91]
    unsigned char* o = h0 + (size_t)(m0 + quad * 4) * HIDD + wave * 32 + l15;
#pragma unroll
    for (int r = 0; r < 4; ++r) {
      o[(size_t)r * HIDD]      = f2fp8(c0[r]);
      o[(size_t)r * HIDD + 16] = f2fp8(c1[r]);
    }
  }
}

// ---------------- GEMM2 (MFMA): z0(bf16) = h(bf16) @ w2  [100000x256 @ 256x64]
__global__ __launch_bounds__(256) void gemm2_mfma(
    const unsigned short* __restrict__ hb, const unsigned short* __restrict__ w2s,
    unsigned short* __restrict__ z0) {
  const int lane = threadIdx.x & 63;
  const int wave = threadIdx.x >> 6;   // 0..3
  const int quad = lane >> 4;
  const int l15  = lane & 15;
  const short8* w2v = (const short8*)w2s;
  short8 bf[8];
#pragma unroll
  for (int kt = 0; kt < 8; ++kt)
    bf[kt] = w2v[(size_t)(kt * 4 + wave) * 64 + lane];
  for (int i = 0; i < 10; ++i) {
    const int m0 = (blockIdx.x * 10 + i) * 16;
    const unsigned short* ap = hb + (size_t)(m0 + l15) * HIDD + quad * 8;
    short8 af[8];
#pragma unroll
    for (int kt = 0; kt < 8; ++kt)
      af[kt] = *(const short8*)(ap + kt * 32);
    floatx4 c = {0.f, 0.f, 0.f, 0.f};
#pragma unroll
    for (int kt = 0; kt < 8; ++kt)
      c = __builtin_amdgcn_mfma_f32_16x16x32_bf16(af[kt], bf[kt], c, 0, 0, 0);
    unsigned short* o = z0 + (size_t)(m0 + quad * 4) * EMBD + wave * 16 + l15;
#pragma unroll
    for (int r = 0; r < 4; ++r) o[(size_t)r * EMBD] = f2bf(c[r]);
  }
}

// ---------------- CSR build --------------------------------------------------
__global__ void hist_kernel(const int* __restrict__ row, int* __restrict__ cnt) {
  int e = blockIdx.x * blockDim.x + threadIdx.x;
  if (e < EE) atomicAdd(&cnt[row[e]], 1);
}

__global__ __launch_bounds__(1024) void scan1_kernel(
    const int* __restrict__ cnt, int* __restrict__ tmp, int* __restrict__ bsum) {
  __shared__ int lds[1024];
  int gid = blockIdx.x * 1024 + threadIdx.x;
  int v = (gid < NN) ? cnt[gid] : 0;
  lds[threadIdx.x] = v;
  for (int off = 1; off < 1024; off <<= 1) {
    __syncthreads();
    int t = (threadIdx.x >= off) ? lds[threadIdx.x - off] : 0;
    __syncthreads();
    lds[threadIdx.x] += t;
  }
  __syncthreads();
  if (gid < NN) tmp[gid] = lds[threadIdx.x];
  if (threadIdx.x == 1023) bsum[blockIdx.x] = lds[1023];
}

__global__ __launch_bounds__(128) void scan2_kernel(
    const int* __restrict__ bsum, int* __restrict__ bpre) {
  __shared__ int lds[128];
  const int nb = (NN + 1023) / 1024;  // 98
  int v = (threadIdx.x < nb) ? bsum[threadIdx.x] : 0;
  lds[threadIdx.x] = v;
  for (int off = 1; off < 128; off <<= 1) {
    __syncthreads();
    int t = (threadIdx.x >= off) ? lds[threadIdx.x - off] : 0;
    __syncthreads();
    lds[threadIdx.x] += t;
  }
  __syncthreads();
  if (threadIdx.x < nb) bpre[threadIdx.x] = lds[threadIdx.x] - v;  // exclusive
}

__global__ __launch_bounds__(1024) void scan3_kernel(
    const int* __restrict__ tmp, const int* __restrict__ cnt,
    const int* __restrict__ bpre, int* __restrict__ row_start,
    int* __restrict__ cursor) {
  int gid = blockIdx.x * 1024 + threadIdx.x;
  if (gid < NN) {
    int ex = tmp[gid] - cnt[gid] + bpre[blockIdx.x];  // exclusive scan
    row_start[gid] = ex;
    cursor[gid] = ex;
  }
  if (gid == 0) row_start[NN] = EE;
}

// pack (col, val) into one int2 per edge: one 8B store, one broadcast load later
__global__ void scatter_kernel(
    const int* __restrict__ row, const int* __restrict__ col,
    const float* __restrict__ val, int* __restrict__ cursor,
    int2* __restrict__ edges) {
  int e = blockIdx.x * blockDim.x + threadIdx.x;
  if (e < EE) {
    int r = row[e];
    int p = atomicAdd(&cursor[r], 1);
    int2 pk; pk.x = col[e]; pk.y = __float_as_int(val[e]);
    edges[p] = pk;
  }
}

// ---------------- SpMM1 + BN1 + ReLU: h(bf16) = relu(bn1(A @ h0(fp8))) -------
// One wave per row. Lane i owns dims 4i..4i+3 (one fp8 dword gather per edge).
// Edge loop unrolled x4: 4 independent gathers in flight per wave.
__global__ __launch_bounds__(256) void spmm1_kernel(
    const unsigned char* __restrict__ h0, const int* __restrict__ row_start,
    const int2* __restrict__ edges,
    const float* __restrict__ gamma, const float* __restrict__ beta,
    const float* __restrict__ mean, const float* __restrict__ var,
    unsigned short* __restrict__ h) {
  const int row  = (blockIdx.x * blockDim.x + threadIdx.x) >> 6;
  const int lane = threadIdx.x & 63;
  const int s = row_start[row];
  const int e = row_start[row + 1];
  float a0 = 0.f, a1 = 0.f, a2 = 0.f, a3 = 0.f;
  int p = s;
  for (; p + 4 <= e; p += 4) {
    int2 e0 = edges[p];
    int2 e1 = edges[p + 1];
    int2 e2 = edges[p + 2];
    int2 e3 = edges[p + 3];
    unsigned g0 = *(const unsigned*)(h0 + (size_t)e0.x * HIDD + lane * 4);
    unsigned g1 = *(const unsigned*)(h0 + (size_t)e1.x * HIDD + lane * 4);
    unsigned g2 = *(const unsigned*)(h0 + (size_t)e2.x * HIDD + lane * 4);
    unsigned g3 = *(const unsigned*)(h0 + (size_t)e3.x * HIDD + lane * 4);
    const float v0 = __int_as_float(e0.y);
    const float v1 = __int_as_float(e1.y);
    const float v2 = __int_as_float(e2.y);
    const float v3 = __int_as_float(e3.y);
    a0 = fmaf(v0, __builtin_amdgcn_cvt_f32_fp8(g0, 0), a0);
    a1 = fmaf(v0, __builtin_amdgcn_cvt_f32_fp8(g0, 1), a1);
    a2 = fmaf(v0, __builtin_amdgcn_cvt_f32_fp8(g0, 2), a2);
    a3 = fmaf(v0, __builtin_amdgcn_cvt_f32_fp8(g0, 3), a3);
    a0 = fmaf(v1, __builtin_amdgcn_cvt_f32_fp8(g1, 0), a0);
    a1 = fmaf(v1, __builtin_amdgcn_cvt_f32_fp8(g1, 1), a1);
    a2 = fmaf(v1, __builtin_amdgcn_cvt_f32_fp8(g1, 2), a2);
    a3 = fmaf(v1, __builtin_amdgcn_cvt_f32_fp8(g1, 3), a3);
    a0 = fmaf(v2, __builtin_amdgcn_cvt_f32_fp8(g2, 0), a0);
    a1 = fmaf(v2, __builtin_amdgcn_cvt_f32_fp8(g2, 1), a1);
    a2 = fmaf(v2, __builtin_amdgcn_cvt_f32_fp8(g2, 2), a2);
    a3 = fmaf(v2, __builtin_amdgcn_cvt_f32_fp8(g2, 3), a3);
    a0 = fmaf(v3, __builtin_amdgcn_cvt_f32_fp8(g3, 0), a0);
    a1 = fmaf(v3, __builtin_amdgcn_cvt_f32_fp8(g3, 1), a1);
    a2 = fmaf(v3, __builtin_amdgcn_cvt_f32_fp8(g3, 2), a2);
    a3 = fmaf(v3, __builtin_amdgcn_cvt_f32_fp8(g3, 3), a3);
  }
  for (; p < e; ++p) {
    int2 e0 = edges[p];
    unsigned g0 = *(const unsigned*)(h0 + (size_t)e0.x * HIDD + lane * 4);
    const float v0 = __int_as_float(e0.y);
    a0 = fmaf(v0, __builtin_amdgcn_cvt_f32_fp8(g0, 0), a0);
    a1 = fmaf(v0, __builtin_amdgcn_cvt_f32_fp8(g0, 1), a1);
    a2 = fmaf(v0, __builtin_amdgcn_cvt_f32_fp8(g0, 2), a2);
    a3 = fmaf(v0, __builtin_amdgcn_cvt_f32_fp8(g0, 3), a3);
  }
  const int d = lane * 4;
  float4 g = *(const float4*)(gamma + d);
  float4 b = *(const float4*)(beta + d);
  float4 m = *(const float4*)(mean + d);
  float4 vv = *(const float4*)(var + d);
  ushort4 o;
  o.x = f2bf(fmaxf(fmaf((a0 - m.x) * rsqrtf(vv.x + EPS_BN), g.x, b.x), 0.f));
  o.y = f2bf(fmaxf(fmaf((a1 - m.y) * rsqrtf(vv.y + EPS_BN), g.y, b.y), 0.f));
  o.z = f2bf(fmaxf(fmaf((a2 - m.z) * rsqrtf(vv.z + EPS_BN), g.z, b.z), 0.f));
  o.w = f2bf(fmaxf(fmaf((a3 - m.w) * rsqrtf(vv.w + EPS_BN), g.w, b.w), 0.f));
  *(ushort4*)(h + (size_t)row * HIDD + d) = o;
}

// ---------------- SpMM2 + BN2: out = bn2(A @ z0(bf16)) -----------------------
// One wave per row; lane = embedding dim. Edge loop unrolled x4.
__global__ __launch_bounds__(256) void spmm2_kernel(
    const unsigned short* __restrict__ z0, const int* __restrict__ row_start,
    const int2* __restrict__ edges,
    const float* __restrict__ gamma, const float* __restrict__ beta,
    const float* __restrict__ mean, const float* __restrict__ var,
    float* __restrict__ out) {
  const int row  = (blockIdx.x * blockDim.x + threadIdx.x) >> 6;
  const int lane = threadIdx.x & 63;
  const int s = row_start[row];
  const int e = row_start[row + 1];
  float acc = 0.f;
  int p = s;
  for (; p + 4 <= e; p += 4) {
    int2 e0 = edges[p];
    int2 e1 = edges[p + 1];
    int2 e2 = edges[p + 2];
    int2 e3 = edges[p + 3];
    unsigned short g0 = z0[(size_t)e0.x * EMBD + lane];
    unsigned short g1 = z0[(size_t)e1.x * EMBD + lane];
    unsigned short g2 = z0[(size_t)e2.x * EMBD + lane];
    unsigned short g3 = z0[(size_t)e3.x * EMBD + lane];
    acc = fmaf(__int_as_float(e0.y), bf2f(g0), acc);
    acc = fmaf(__int_as_float(e1.y), bf2f(g1), acc);
    acc = fmaf(__int_as_float(e2.y), bf2f(g2), acc);
    acc = fmaf(__int_as_float(e3.y), bf2f(g3), acc);
  }
  for (; p < e; ++p) {
    int2 e0 = edges[p];
    acc = fmaf(__int_as_float(e0.y), bf2f(z0[(size_t)e0.x * EMBD + lane]), acc);
  }
  float r = fmaf((acc - mean[lane]) * rsqrtf(var[lane] + EPS_BN), gamma[lane],
                 beta[lane]);
  out[(size_t)row * EMBD + lane] = r;
}

extern "C" void kernel_launch(void* const* d_in, const int* in_sizes, int n_in,
                              void* d_out, int out_size, void* d_ws, size_t ws_size,
                              hipStream_t stream) {
  const float* x        = (const float*)d_in[0];
  const int*   edge_row = (const int*)d_in[1];
  const int*   edge_col = (const int*)d_in[2];
  const float* edge_val = (const float*)d_in[3];
  const float* w1       = (const float*)d_in[4];
  const float* w2       = (const float*)d_in[5];
  const float* gamma1   = (const float*)d_in[6];
  const float* beta1    = (const float*)d_in[7];
  const float* mean1    = (const float*)d_in[8];
  const float* var1     = (const float*)d_in[9];
  const float* gamma2   = (const float*)d_in[10];
  const float* beta2    = (const float*)d_in[11];
  const float* mean2    = (const float*)d_in[12];
  const float* var2     = (const float*)d_in[13];
  float* out = (float*)d_out;

  // Workspace layout (256B aligned). Total ~168 MB.
  char* ws = (char*)d_ws;
  size_t off = 0;
  auto alloc = [&](size_t bytes) -> void* {
    void* p = ws + off;
    off = (off + bytes + 255) & ~(size_t)255;
    return p;
  };
  unsigned short* xb  = (unsigned short*)alloc((size_t)NN * IND * 2);   // 51.2MB
  unsigned char*  h0  = (unsigned char*)alloc((size_t)NN * HIDD);       // 25.6MB fp8
  unsigned short* h   = (unsigned short*)alloc((size_t)NN * HIDD * 2);  // 51.2MB bf16
  unsigned short* z0  = (unsigned short*)alloc((size_t)NN * EMBD * 2);  // 12.8MB bf16
  unsigned short* w1s = (unsigned short*)alloc((size_t)IND * HIDD * 2);
  unsigned short* w2s = (unsigned short*)alloc((size_t)HIDD * EMBD * 2);
  int*   cnt      = (int*)alloc((size_t)NN * 4);
  int*   tmp      = (int*)alloc((size_t)NN * 4);
  int*   bsum     = (int*)alloc(128 * 4);
  int*   bpre     = (int*)alloc(128 * 4);
  int*   row_start= (int*)alloc((size_t)(NN + 1) * 4);
  int*   cursor   = (int*)alloc((size_t)NN * 4);
  int2*  edges    = (int2*)alloc((size_t)EE * 8);                       // 25.6MB

  const int nb_scan = (NN + 1023) / 1024;  // 98

  // casts + weight swizzles (independent of CSR build)
  cast_x_kernel<<<(NN * IND / 4) / 256, 256, 0, stream>>>(x, xb);
  swz_w1_kernel<<<8192 / 256, 256, 0, stream>>>(w1, w1s);
  swz_w2_kernel<<<2048 / 256, 256, 0, stream>>>(w2, w2s);

  // CSR build
  hipMemsetAsync(cnt, 0, (size_t)NN * 4, stream);
  hist_kernel<<<(EE + 255) / 256, 256, 0, stream>>>(edge_row, cnt);
  scan1_kernel<<<nb_scan, 1024, 0, stream>>>(cnt, tmp, bsum);
  scan2_kernel<<<1, 128, 0, stream>>>(bsum, bpre);
  scan3_kernel<<<nb_scan, 1024, 0, stream>>>(tmp, cnt, bpre, row_start, cursor);
  scatter_kernel<<<(EE + 255) / 256, 256, 0, stream>>>(
      edge_row, edge_col, edge_val, cursor, edges);

  // Layer 1: h0 = fp8(xb @ w1) ; h = bf16(relu(bn1(A @ h0)))
  gemm1_mfma<<<625, 512, 0, stream>>>(xb, w1s, h0);
  spmm1_kernel<<<NN / 4, 256, 0, stream>>>(h0, row_start, edges,
                                           gamma1, beta1, mean1, var1, h);
  // Layer 2: z0 = bf16(h @ w2) ; out = bn2(A @ z0)
  gemm2_mfma<<<625, 256, 0, stream>>>(h, w2s, z0);
  spmm2_kernel<<<NN / 4, 256, 0, stream>>>(z0, row_start, edges,
                                           gamma2, beta2, mean2, var2, out);
}